// Round 2
// baseline (2370.285 us; speedup 1.0000x reference)
//
#include <hip/hip_runtime.h>

#define NN 100000
#define NE 1200000
#define DIM 64

// Y <- Y - ALP*( (Y-x)/(D0+D1) + LAM*(Y-nAX0) - (LAM_K/K)*(Y-nAX1) )
// ALP=0.5, LAM=1, LAM_K/K=0.125

__global__ void deg_hist(const int* __restrict__ dst0, const int* __restrict__ dst1,
                         int* __restrict__ deg0, int* __restrict__ deg1) {
    int e = blockIdx.x * blockDim.x + threadIdx.x;
    if (e < NE) {
        atomicAdd(&deg0[dst0[e]], 1);
        atomicAdd(&deg1[dst1[e]], 1);
    }
}

// Single-block exclusive scan over both degree arrays -> row starts.
__global__ void __launch_bounds__(1024) scan_rows(const int* __restrict__ deg0,
                                                  const int* __restrict__ deg1,
                                                  int* __restrict__ rs0,
                                                  int* __restrict__ rs1) {
    __shared__ int s0[1024], s1[1024];
    const int CH = (NN + 1023) / 1024;  // 98 nodes per thread
    int t = threadIdx.x;
    int lo = t * CH, hi = lo + CH;
    if (lo > NN) lo = NN;
    if (hi > NN) hi = NN;
    int a = 0, b = 0;
    for (int i = lo; i < hi; ++i) { a += deg0[i]; b += deg1[i]; }
    s0[t] = a; s1[t] = b;
    __syncthreads();
    for (int off = 1; off < 1024; off <<= 1) {
        int x0 = (t >= off) ? s0[t - off] : 0;
        int x1 = (t >= off) ? s1[t - off] : 0;
        __syncthreads();
        s0[t] += x0; s1[t] += x1;
        __syncthreads();
    }
    int base0 = (t > 0) ? s0[t - 1] : 0;
    int base1 = (t > 0) ? s1[t - 1] : 0;
    for (int i = lo; i < hi; ++i) {
        rs0[i] = base0; base0 += deg0[i];
        rs1[i] = base1; base1 += deg1[i];
    }
}

__global__ void node_params(const int* __restrict__ deg0, const int* __restrict__ deg1,
                            float* __restrict__ inv0, float* __restrict__ inv1,
                            float* __restrict__ recipD) {
    int n = blockIdx.x * blockDim.x + threadIdx.x;
    if (n < NN) {
        int a = deg0[n], b = deg1[n];
        inv0[n] = (a > 0) ? rsqrtf((float)a) : 0.0f;
        inv1[n] = (b > 0) ? rsqrtf((float)b) : 0.0f;
        int s = a + b;
        recipD[n] = (s > 0) ? 1.0f / (float)s : 0.0f;
    }
}

__global__ void scatter_edges(const int* __restrict__ src0, const int* __restrict__ dst0,
                              const int* __restrict__ src1, const int* __restrict__ dst1,
                              const int* __restrict__ rs0, const int* __restrict__ rs1,
                              int* __restrict__ cur0, int* __restrict__ cur1,
                              int* __restrict__ es0, int* __restrict__ es1) {
    int e = blockIdx.x * blockDim.x + threadIdx.x;
    if (e < NE) {
        int d = dst0[e];
        int p = atomicAdd(&cur0[d], 1);
        es0[rs0[d] + p] = src0[e];
        d = dst1[e];
        p = atomicAdd(&cur1[d], 1);
        es1[rs1[d] + p] = src1[e];
    }
}

// One wave (64 lanes = 64 features) per node; 4 nodes per 256-thread block.
__global__ void __launch_bounds__(256) step_kernel(
    const float* __restrict__ Yin, const float* __restrict__ X,
    const int* __restrict__ rs0, const int* __restrict__ deg0,
    const int* __restrict__ es0, const float* __restrict__ inv0,
    const int* __restrict__ rs1, const int* __restrict__ deg1,
    const int* __restrict__ es1, const float* __restrict__ inv1,
    const float* __restrict__ recipD, float* __restrict__ Yout)
{
    int node = blockIdx.x * 4 + (threadIdx.x >> 6);
    int d = threadIdx.x & 63;
    if (node >= NN) return;

    float acc0 = 0.0f;
    {
        int s = rs0[node], c = deg0[node];
        for (int i = 0; i < c; ++i) {
            int src = es0[s + i];
            acc0 = fmaf(Yin[src * DIM + d], inv0[src], acc0);
        }
    }
    float acc1 = 0.0f;
    {
        int s = rs1[node], c = deg1[node];
        for (int i = 0; i < c; ++i) {
            int src = es1[s + i];
            acc1 = fmaf(Yin[src * DIM + d], inv1[src], acc1);
        }
    }
    float a0 = inv0[node] * acc0;
    float a1 = inv1[node] * acc1;
    float y  = Yin[node * DIM + d];
    float xx = X[node * DIM + d];
    float out = y - 0.5f * ((y - xx) * recipD[node] + (y - a0) - 0.125f * (y - a1));
    Yout[node * DIM + d] = out;
}

extern "C" void kernel_launch(void* const* d_in, const int* in_sizes, int n_in,
                              void* d_out, int out_size, void* d_ws, size_t ws_size,
                              hipStream_t stream) {
    const float* x   = (const float*)d_in[0];
    const int* src0  = (const int*)d_in[1];
    const int* dst0  = (const int*)d_in[2];
    const int* src1  = (const int*)d_in[3];
    const int* dst1  = (const int*)d_in[4];
    float* out = (float*)d_out;

    char* ws = (char*)d_ws;
    size_t off = 0;
    auto alloc = [&](size_t bytes) -> void* {
        void* p = ws + off;
        off += (bytes + 255) & ~(size_t)255;
        return p;
    };

    float* W    = (float*)alloc((size_t)NN * DIM * 4);
    int*   es0  = (int*)alloc((size_t)NE * 4);
    int*   es1  = (int*)alloc((size_t)NE * 4);
    // Four atomic-counter arrays in ONE allocation so a single exact-size
    // memset covers them (previous round: per-array 256B padding made a
    // combined memset fall 384B short -> poisoned cur1 -> OOB scatter).
    int*   cnt  = (int*)alloc((size_t)4 * NN * 4);
    int*   deg0 = cnt;
    int*   deg1 = cnt + NN;
    int*   cur0 = cnt + 2 * NN;
    int*   cur1 = cnt + 3 * NN;
    int*   rs0  = (int*)alloc((size_t)NN * 4);
    int*   rs1  = (int*)alloc((size_t)NN * 4);
    float* inv0 = (float*)alloc((size_t)NN * 4);
    float* inv1 = (float*)alloc((size_t)NN * 4);
    float* rD   = (float*)alloc((size_t)NN * 4);

    hipMemsetAsync(cnt, 0, (size_t)4 * NN * 4, stream);

    const int TB = 256;
    deg_hist<<<(NE + TB - 1) / TB, TB, 0, stream>>>(dst0, dst1, deg0, deg1);
    scan_rows<<<1, 1024, 0, stream>>>(deg0, deg1, rs0, rs1);
    node_params<<<(NN + TB - 1) / TB, TB, 0, stream>>>(deg0, deg1, inv0, inv1, rD);
    scatter_edges<<<(NE + TB - 1) / TB, TB, 0, stream>>>(src0, dst0, src1, dst1,
                                                         rs0, rs1, cur0, cur1, es0, es1);

    int grid = (NN + 3) / 4;  // 4 nodes per block
    const float* cur = x;
    for (int i = 0; i < 8; ++i) {
        float* dst = (i & 1) ? out : W;
        step_kernel<<<grid, TB, 0, stream>>>(cur, x,
                                             rs0, deg0, es0, inv0,
                                             rs1, deg1, es1, inv1,
                                             rD, dst);
        cur = dst;
    }
}

// Round 3
// 1060.805 us; speedup vs baseline: 2.2344x; 2.2344x over previous
//
#include <hip/hip_runtime.h>

#define NN 100000
#define NE 1200000
#define DIM 64
#define NBLK ((NN + 255) / 256)   // 391 level-1 scan blocks

// Y <- Y - 0.5*( (Y-x)/(D0+D1) + (Y-nAX0) - 0.125*(Y-nAX1) )

__global__ void deg_hist(const int* __restrict__ dst0, const int* __restrict__ dst1,
                         int* __restrict__ deg0, int* __restrict__ deg1) {
    int e = blockIdx.x * blockDim.x + threadIdx.x;
    if (e < NE) {
        atomicAdd(&deg0[dst0[e]], 1);
        atomicAdd(&deg1[dst1[e]], 1);
    }
}

// ---- 3-level device-wide exclusive scan of deg0/deg1 -> rs0/rs1 ----
__global__ void __launch_bounds__(256) scan_l1(const int* __restrict__ deg0,
                                               const int* __restrict__ deg1,
                                               int* __restrict__ rs0, int* __restrict__ rs1,
                                               int* __restrict__ bs0, int* __restrict__ bs1) {
    __shared__ int s0[256], s1[256];
    int t = threadIdx.x;
    int n = blockIdx.x * 256 + t;
    int a = (n < NN) ? deg0[n] : 0;
    int b = (n < NN) ? deg1[n] : 0;
    s0[t] = a; s1[t] = b;
    __syncthreads();
    for (int off = 1; off < 256; off <<= 1) {
        int x0 = (t >= off) ? s0[t - off] : 0;
        int x1 = (t >= off) ? s1[t - off] : 0;
        __syncthreads();
        s0[t] += x0; s1[t] += x1;
        __syncthreads();
    }
    if (n < NN) {
        rs0[n] = s0[t] - a;    // exclusive within block
        rs1[n] = s1[t] - b;
    }
    if (t == 255) { bs0[blockIdx.x] = s0[255]; bs1[blockIdx.x] = s1[255]; }
}

__global__ void __launch_bounds__(512) scan_l2(int* __restrict__ bs0, int* __restrict__ bs1) {
    __shared__ int s0[512], s1[512];
    int t = threadIdx.x;
    int a = (t < NBLK) ? bs0[t] : 0;
    int b = (t < NBLK) ? bs1[t] : 0;
    s0[t] = a; s1[t] = b;
    __syncthreads();
    for (int off = 1; off < 512; off <<= 1) {
        int x0 = (t >= off) ? s0[t - off] : 0;
        int x1 = (t >= off) ? s1[t - off] : 0;
        __syncthreads();
        s0[t] += x0; s1[t] += x1;
        __syncthreads();
    }
    if (t < NBLK) { bs0[t] = s0[t] - a; bs1[t] = s1[t] - b; }  // exclusive
}

__global__ void __launch_bounds__(256) scan_l3(int* __restrict__ rs0, int* __restrict__ rs1,
                                               const int* __restrict__ bs0,
                                               const int* __restrict__ bs1) {
    int n = blockIdx.x * 256 + threadIdx.x;
    if (n < NN) {
        rs0[n] += bs0[blockIdx.x];
        rs1[n] += bs1[blockIdx.x];
    }
}

__global__ void node_params(const int* __restrict__ deg0, const int* __restrict__ deg1,
                            float* __restrict__ inv0, float* __restrict__ inv1,
                            float* __restrict__ recipD) {
    int n = blockIdx.x * blockDim.x + threadIdx.x;
    if (n < NN) {
        int a = deg0[n], b = deg1[n];
        inv0[n] = (a > 0) ? rsqrtf((float)a) : 0.0f;
        inv1[n] = (b > 0) ? rsqrtf((float)b) : 0.0f;
        int s = a + b;
        recipD[n] = (s > 0) ? 1.0f / (float)s : 0.0f;
    }
}

// Pack (src, inv[src]) per edge so the step loop has no dependent weight gather.
__global__ void scatter_edges(const int* __restrict__ src0, const int* __restrict__ dst0,
                              const int* __restrict__ src1, const int* __restrict__ dst1,
                              const int* __restrict__ rs0, const int* __restrict__ rs1,
                              const float* __restrict__ inv0, const float* __restrict__ inv1,
                              int* __restrict__ cur0, int* __restrict__ cur1,
                              int2* __restrict__ es0, int2* __restrict__ es1) {
    int e = blockIdx.x * blockDim.x + threadIdx.x;
    if (e < NE) {
        int s = src0[e], d = dst0[e];
        int p = atomicAdd(&cur0[d], 1);
        es0[rs0[d] + p] = make_int2(s, __float_as_int(inv0[s]));
        s = src1[e]; d = dst1[e];
        p = atomicAdd(&cur1[d], 1);
        es1[rs1[d] + p] = make_int2(s, __float_as_int(inv1[s]));
    }
}

// One wave (64 lanes = 64 features) per node; 4 nodes per 256-thread block.
// Gather loop unrolled x4: 4 independent index loads + 4 independent row gathers
// in flight per iteration.
__global__ void __launch_bounds__(256) step_kernel(
    const float* __restrict__ Yin, const float* __restrict__ X,
    const int* __restrict__ rs0, const int* __restrict__ deg0,
    const int2* __restrict__ es0, const float* __restrict__ inv0,
    const int* __restrict__ rs1, const int* __restrict__ deg1,
    const int2* __restrict__ es1, const float* __restrict__ inv1,
    const float* __restrict__ recipD, float* __restrict__ Yout)
{
    int node = blockIdx.x * 4 + (threadIdx.x >> 6);
    int d = threadIdx.x & 63;
    if (node >= NN) return;

    float acc0 = 0.0f;
    {
        int s = rs0[node], c = deg0[node];
        int i = 0;
        for (; i + 4 <= c; i += 4) {
            int2 e0 = es0[s + i + 0];
            int2 e1 = es0[s + i + 1];
            int2 e2 = es0[s + i + 2];
            int2 e3 = es0[s + i + 3];
            float y0 = Yin[e0.x * DIM + d];
            float y1 = Yin[e1.x * DIM + d];
            float y2 = Yin[e2.x * DIM + d];
            float y3 = Yin[e3.x * DIM + d];
            acc0 = fmaf(y0, __int_as_float(e0.y), acc0);
            acc0 = fmaf(y1, __int_as_float(e1.y), acc0);
            acc0 = fmaf(y2, __int_as_float(e2.y), acc0);
            acc0 = fmaf(y3, __int_as_float(e3.y), acc0);
        }
        for (; i < c; ++i) {
            int2 e = es0[s + i];
            acc0 = fmaf(Yin[e.x * DIM + d], __int_as_float(e.y), acc0);
        }
    }
    float acc1 = 0.0f;
    {
        int s = rs1[node], c = deg1[node];
        int i = 0;
        for (; i + 4 <= c; i += 4) {
            int2 e0 = es1[s + i + 0];
            int2 e1 = es1[s + i + 1];
            int2 e2 = es1[s + i + 2];
            int2 e3 = es1[s + i + 3];
            float y0 = Yin[e0.x * DIM + d];
            float y1 = Yin[e1.x * DIM + d];
            float y2 = Yin[e2.x * DIM + d];
            float y3 = Yin[e3.x * DIM + d];
            acc1 = fmaf(y0, __int_as_float(e0.y), acc1);
            acc1 = fmaf(y1, __int_as_float(e1.y), acc1);
            acc1 = fmaf(y2, __int_as_float(e2.y), acc1);
            acc1 = fmaf(y3, __int_as_float(e3.y), acc1);
        }
        for (; i < c; ++i) {
            int2 e = es1[s + i];
            acc1 = fmaf(Yin[e.x * DIM + d], __int_as_float(e.y), acc1);
        }
    }
    float a0 = inv0[node] * acc0;
    float a1 = inv1[node] * acc1;
    float y  = Yin[node * DIM + d];
    float xx = X[node * DIM + d];
    float out = y - 0.5f * ((y - xx) * recipD[node] + (y - a0) - 0.125f * (y - a1));
    Yout[node * DIM + d] = out;
}

extern "C" void kernel_launch(void* const* d_in, const int* in_sizes, int n_in,
                              void* d_out, int out_size, void* d_ws, size_t ws_size,
                              hipStream_t stream) {
    const float* x   = (const float*)d_in[0];
    const int* src0  = (const int*)d_in[1];
    const int* dst0  = (const int*)d_in[2];
    const int* src1  = (const int*)d_in[3];
    const int* dst1  = (const int*)d_in[4];
    float* out = (float*)d_out;

    char* ws = (char*)d_ws;
    size_t off = 0;
    auto alloc = [&](size_t bytes) -> void* {
        void* p = ws + off;
        off += (bytes + 255) & ~(size_t)255;
        return p;
    };

    float* W    = (float*)alloc((size_t)NN * DIM * 4);
    int2*  es0  = (int2*)alloc((size_t)NE * 8);
    int2*  es1  = (int2*)alloc((size_t)NE * 8);
    // deg0,deg1,cur0,cur1 in ONE allocation -> single exact-size memset.
    int*   cnt  = (int*)alloc((size_t)4 * NN * 4);
    int*   deg0 = cnt;
    int*   deg1 = cnt + NN;
    int*   cur0 = cnt + 2 * NN;
    int*   cur1 = cnt + 3 * NN;
    int*   rs0  = (int*)alloc((size_t)NN * 4);
    int*   rs1  = (int*)alloc((size_t)NN * 4);
    float* inv0 = (float*)alloc((size_t)NN * 4);
    float* inv1 = (float*)alloc((size_t)NN * 4);
    float* rD   = (float*)alloc((size_t)NN * 4);
    int*   bs0  = (int*)alloc((size_t)NBLK * 4);
    int*   bs1  = (int*)alloc((size_t)NBLK * 4);

    hipMemsetAsync(cnt, 0, (size_t)4 * NN * 4, stream);

    const int TB = 256;
    deg_hist<<<(NE + TB - 1) / TB, TB, 0, stream>>>(dst0, dst1, deg0, deg1);
    scan_l1<<<NBLK, 256, 0, stream>>>(deg0, deg1, rs0, rs1, bs0, bs1);
    scan_l2<<<1, 512, 0, stream>>>(bs0, bs1);
    scan_l3<<<NBLK, 256, 0, stream>>>(rs0, rs1, bs0, bs1);
    node_params<<<(NN + TB - 1) / TB, TB, 0, stream>>>(deg0, deg1, inv0, inv1, rD);
    scatter_edges<<<(NE + TB - 1) / TB, TB, 0, stream>>>(src0, dst0, src1, dst1,
                                                         rs0, rs1, inv0, inv1,
                                                         cur0, cur1, es0, es1);

    int grid = (NN + 3) / 4;  // 4 nodes per block
    const float* cur = x;
    for (int i = 0; i < 8; ++i) {
        float* dst = (i & 1) ? out : W;
        step_kernel<<<grid, TB, 0, stream>>>(cur, x,
                                             rs0, deg0, es0, inv0,
                                             rs1, deg1, es1, inv1,
                                             rD, dst);
        cur = dst;
    }
}

// Round 4
// 886.559 us; speedup vs baseline: 2.6736x; 1.1965x over previous
//
#include <hip/hip_runtime.h>

#define NN 100000
#define NE 1200000
#define DIM 64
#define NBLK ((NN + 255) / 256)   // 391 level-1 scan blocks

// out = (0.5625 - 0.5*rD)*y + 0.5*rD*x + sum_e w_e * Y[src_e]
//   graph0 edge: w = +0.5    * inv0[dst]*inv0[src]
//   graph1 edge: w = -0.0625 * inv1[dst]*inv1[src]

__global__ void deg_hist(const int* __restrict__ dst0, const int* __restrict__ dst1,
                         int* __restrict__ deg0, int* __restrict__ deg1) {
    int e = blockIdx.x * blockDim.x + threadIdx.x;
    if (e < NE) {
        atomicAdd(&deg0[dst0[e]], 1);
        atomicAdd(&deg1[dst1[e]], 1);
    }
}

// Scan of PADDED merged degree: dp[n] = roundup8(deg0+deg1); rs = exclusive scan.
__global__ void __launch_bounds__(256) scan_l1(const int* __restrict__ deg0,
                                               const int* __restrict__ deg1,
                                               int* __restrict__ rs, int* __restrict__ dp,
                                               int* __restrict__ bs) {
    __shared__ int s0[256];
    int t = threadIdx.x;
    int n = blockIdx.x * 256 + t;
    int a = 0;
    if (n < NN) a = (deg0[n] + deg1[n] + 7) & ~7;
    s0[t] = a;
    __syncthreads();
    for (int off = 1; off < 256; off <<= 1) {
        int x0 = (t >= off) ? s0[t - off] : 0;
        __syncthreads();
        s0[t] += x0;
        __syncthreads();
    }
    if (n < NN) { rs[n] = s0[t] - a; dp[n] = a; }
    if (t == 255) bs[blockIdx.x] = s0[255];
}

__global__ void __launch_bounds__(512) scan_l2(int* __restrict__ bs) {
    __shared__ int s0[512];
    int t = threadIdx.x;
    int a = (t < NBLK) ? bs[t] : 0;
    s0[t] = a;
    __syncthreads();
    for (int off = 1; off < 512; off <<= 1) {
        int x0 = (t >= off) ? s0[t - off] : 0;
        __syncthreads();
        s0[t] += x0;
        __syncthreads();
    }
    if (t < NBLK) bs[t] = s0[t] - a;  // exclusive
}

__global__ void __launch_bounds__(256) scan_l3(int* __restrict__ rs, const int* __restrict__ bs) {
    int n = blockIdx.x * 256 + threadIdx.x;
    if (n < NN) rs[n] += bs[blockIdx.x];
}

__global__ void node_params(const int* __restrict__ deg0, const int* __restrict__ deg1,
                            float* __restrict__ inv0, float* __restrict__ inv1,
                            float2* __restrict__ cf) {
    int n = blockIdx.x * blockDim.x + threadIdx.x;
    if (n < NN) {
        int a = deg0[n], b = deg1[n];
        inv0[n] = (a > 0) ? rsqrtf((float)a) : 0.0f;
        inv1[n] = (b > 0) ? rsqrtf((float)b) : 0.0f;
        int s = a + b;
        float rD = (s > 0) ? 1.0f / (float)s : 0.0f;
        cf[n] = make_float2(0.5625f - 0.5f * rD, 0.5f * rD);
    }
}

// Merged scatter: both graphs' edges into one padded CSR with folded weights.
__global__ void scatter_edges(const int* __restrict__ src0, const int* __restrict__ dst0,
                              const int* __restrict__ src1, const int* __restrict__ dst1,
                              const int* __restrict__ rs,
                              const float* __restrict__ inv0, const float* __restrict__ inv1,
                              int* __restrict__ cur, int2* __restrict__ es) {
    int e = blockIdx.x * blockDim.x + threadIdx.x;
    if (e < NE) {
        int s = src0[e], d = dst0[e];
        float w = 0.5f * inv0[d] * inv0[s];
        int p = atomicAdd(&cur[d], 1);
        es[rs[d] + p] = make_int2(s, __float_as_int(w));
        s = src1[e]; d = dst1[e];
        w = -0.0625f * inv1[d] * inv1[s];
        p = atomicAdd(&cur[d], 1);
        es[rs[d] + p] = make_int2(s, __float_as_int(w));
    }
}

// One wave per node (64 lanes = 64 features); 4 nodes / 256-thread block.
// Padded degree -> exact batches of 8 independent gathers, no tail.
__global__ void __launch_bounds__(256) step_kernel(
    const float* __restrict__ Yin, const float* __restrict__ X,
    const int* __restrict__ rs, const int* __restrict__ dp,
    const int2* __restrict__ es, const float2* __restrict__ cf,
    float* __restrict__ Yout)
{
    int node = blockIdx.x * 4 + (threadIdx.x >> 6);
    int d = threadIdx.x & 63;
    if (node >= NN) return;
    // node is wave-uniform by construction; pin it to SGPR so CSR metadata
    // and edge-list loads go down the scalar-memory path.
    int un = __builtin_amdgcn_readfirstlane(node);
    int s  = __builtin_amdgcn_readfirstlane(rs[un]);
    int c  = __builtin_amdgcn_readfirstlane(dp[un]);

    const float* yrow = Yin + (size_t)un * DIM;
    float y  = yrow[d];
    float xx = X[(size_t)un * DIM + d];
    float2 cc = cf[un];

    float acc = 0.0f;
    for (int i = 0; i < c; i += 8) {
        int2 eb[8];
#pragma unroll
        for (int k = 0; k < 8; ++k) eb[k] = es[s + i + k];
        float yv[8];
#pragma unroll
        for (int k = 0; k < 8; ++k) yv[k] = Yin[(size_t)eb[k].x * DIM + d];
#pragma unroll
        for (int k = 0; k < 8; ++k) acc = fmaf(yv[k], __int_as_float(eb[k].y), acc);
    }
    Yout[(size_t)un * DIM + d] = cc.x * y + cc.y * xx + acc;
}

extern "C" void kernel_launch(void* const* d_in, const int* in_sizes, int n_in,
                              void* d_out, int out_size, void* d_ws, size_t ws_size,
                              hipStream_t stream) {
    const float* x   = (const float*)d_in[0];
    const int* src0  = (const int*)d_in[1];
    const int* dst0  = (const int*)d_in[2];
    const int* src1  = (const int*)d_in[3];
    const int* dst1  = (const int*)d_in[4];
    float* out = (float*)d_out;

    char* ws = (char*)d_ws;
    size_t off = 0;
    auto alloc = [&](size_t bytes) -> void* {
        void* p = ws + off;
        off += (bytes + 255) & ~(size_t)255;
        return p;
    };

    const size_t ES_CAP = (size_t)2 * NE + 8 * NN;  // padded-CSR upper bound

    float* W    = (float*)alloc((size_t)NN * DIM * 4);
    int2*  es   = (int2*)alloc(ES_CAP * 8);
    // deg0,deg1,cur in ONE allocation -> single exact-size memset.
    int*   cnt  = (int*)alloc((size_t)3 * NN * 4);
    int*   deg0 = cnt;
    int*   deg1 = cnt + NN;
    int*   cur  = cnt + 2 * NN;
    int*   rs   = (int*)alloc((size_t)NN * 4);
    int*   dp   = (int*)alloc((size_t)NN * 4);
    float* inv0 = (float*)alloc((size_t)NN * 4);
    float* inv1 = (float*)alloc((size_t)NN * 4);
    float2* cf  = (float2*)alloc((size_t)NN * 8);
    int*   bs   = (int*)alloc((size_t)NBLK * 4);

    hipMemsetAsync(cnt, 0, (size_t)3 * NN * 4, stream);
    hipMemsetAsync(es, 0, ES_CAP * 8, stream);  // pad slots must be {0, 0.0f}

    const int TB = 256;
    deg_hist<<<(NE + TB - 1) / TB, TB, 0, stream>>>(dst0, dst1, deg0, deg1);
    scan_l1<<<NBLK, 256, 0, stream>>>(deg0, deg1, rs, dp, bs);
    scan_l2<<<1, 512, 0, stream>>>(bs);
    scan_l3<<<NBLK, 256, 0, stream>>>(rs, bs);
    node_params<<<(NN + TB - 1) / TB, TB, 0, stream>>>(deg0, deg1, inv0, inv1, cf);
    scatter_edges<<<(NE + TB - 1) / TB, TB, 0, stream>>>(src0, dst0, src1, dst1,
                                                         rs, inv0, inv1, cur, es);

    int grid = (NN + 3) / 4;  // 4 nodes per block, NN divisible by 4
    const float* curY = x;
    for (int i = 0; i < 8; ++i) {
        float* dst = (i & 1) ? out : W;
        step_kernel<<<grid, TB, 0, stream>>>(curY, x, rs, dp, es, cf, dst);
        curY = dst;
    }
}